// Round 5
// baseline (218.757 us; speedup 1.0000x reference)
//
#include <hip/hip_runtime.h>

// Spherical: out = x * |s|  (x: 8192x4096 fp32, s: scalar fp32)
// Pure streaming scale — memory-bound, zero reuse.
//
// R5: final cell of the cache-hint 2x2, structure frozen at R4's best
// (depth=1, flat exact-cover, 32768 blk x 256 thr):
//   nt load + nt store     ~57-60 us  (R0/R4 best)
//   plain load + nt store  ~85 us     (R2; read-allocate serializes)
//   nt load + PLAIN store  this round
// Evidence for trying plain stores: the harness fill kernel streams
// 512 MiB of plain stores at 6.7 TB/s (84% peak) — L2 write-allocate +
// lazy writeback sustains near-peak and may DECOUPLE the store stream
// from HBM latency (stores retire into L2). With nt loads keeping input
// lines out of L2, store lines churn only themselves = fill's regime.

typedef float fvec4 __attribute__((ext_vector_type(4)));

__global__ __launch_bounds__(256) void spherical_scale_kernel(
    const fvec4* __restrict__ x4,
    const float* __restrict__ s_ptr,
    fvec4* __restrict__ out4,
    int n4)   // number of fvec4 elements
{
    const float s = fabsf(s_ptr[0]);
    const int i = blockIdx.x * blockDim.x + threadIdx.x;

    if (i < n4) {
        fvec4 a = __builtin_nontemporal_load(&x4[i]);
        a *= s;
        out4[i] = a;   // PLAIN store (L2 write-allocate, lazy writeback)
    }
}

extern "C" void kernel_launch(void* const* d_in, const int* in_sizes, int n_in,
                              void* d_out, int out_size, void* d_ws, size_t ws_size,
                              hipStream_t stream) {
    const float* x = (const float*)d_in[0];
    const float* s = (const float*)d_in[1];
    float* out = (float*)d_out;

    const int n = in_sizes[0];        // 8192*4096 = 33554432 floats
    const int n4 = n / 4;             // 8388608 fvec4s
    const int block = 256;
    const int grid = (n4 + block - 1) / block;   // 32768 blocks, 1 fvec4/thread

    spherical_scale_kernel<<<grid, block, 0, stream>>>(
        (const fvec4*)x, s, (fvec4*)out, n4);
}